// Round 1
// baseline (1906.391 us; speedup 1.0000x reference)
//
#include <hip/hip_runtime.h>
#include <hip/hip_fp16.h>
#include <math.h>

#define POUT 7
#define NCH  256
// Per-channel LDS patch capacity (floats). Worst-case needed cells:
// roi_w*roi_h <= (224/8)^2 = 784 cells by the level rule; sampled span is
// 6.5/7 of the roi per axis, +2 for floor/hi borders; maximizing
// (0.93*rw+2)*(0.93*rh+2) under rw*rh<=784, dims<=map gives ~1026 (+1 zero
// cell). 1063 is odd (==7 mod 32) so the 8 channel patches land on
// mixed-parity banks for the clustered compute reads.
#define CAP  1063
#define CHK  8
#define NCHUNK (NCH / CHK)   // 32

// Single-pass multiscale ROIAlign, NCHW-direct. One block per box.
// Per 8-channel chunk: stage the box's bounding patch of each channel plane
// into LDS (coalesced 32-lane row reads), then 49 bins x 8 ch threads
// compute one output bin each from 16 LDS taps. Kills the NCHW->NHWC
// transpose pipeline (218 MB round trip + L3 thrash = ~75% of old time).
__global__ __launch_bounds__(256, 4) void roi_patch_kernel(
    const float* __restrict__ f0, const float* __restrict__ f1,
    const float* __restrict__ f2, const float* __restrict__ f3,
    const float* __restrict__ props, float* __restrict__ out, int boxes_per_img)
{
    __shared__ int4  sRec[196];
    __shared__ __align__(16) float sStage[CHK * 49];
    __shared__ float sPatch[CHK][CAP];

    const int n = blockIdx.x;
    const int t = threadIdx.x;
    const int b = n / boxes_per_img;

    const float4 box = ((const float4*)props)[n];
    const float area = (box.z - box.x) * (box.w - box.y);
    float lvlf = floorf(4.0f + log2f(sqrtf(area) / 224.0f + 1e-6f));
    lvlf = fminf(fmaxf(lvlf, 2.0f), 5.0f) - 2.0f;
    const int l = (int)lvlf;

    const float* feat; int sz;
    if      (l == 0) { feat = f0; sz = 200; }
    else if (l == 1) { feat = f1; sz = 100; }
    else if (l == 2) { feat = f2; sz = 50;  }
    else             { feat = f3; sz = 25;  }
    const int HW = sz * sz;
    const float scale = 0.25f / (float)(1 << l);

    const float x0 = box.x * scale, y0 = box.y * scale;
    const float x1 = box.z * scale, y1 = box.w * scale;
    const float bin_w = fmaxf(x1 - x0, 1.0f) / (float)POUT;
    const float bin_h = fmaxf(y1 - y0, 1.0f) / (float)POUT;

    // ---- patch bounds from the extreme sample offsets (0.25 / 6.75 bins).
    // Same fp expressions as the per-sample prep below; sample coords are
    // monotone in the offset, floor is monotone => all cells land inside.
    const float ys_mn = y0 + 0.25f * bin_h, ys_mx = y0 + 6.75f * bin_h;
    const float xs_mn = x0 + 0.25f * bin_w, xs_mx = x0 + 6.75f * bin_w;
    int v;
    v = (int)floorf(fmaxf(ys_mn, 0.0f)); const int ylo = (v >= sz - 1) ? sz - 1 : v;
    v = (int)floorf(fmaxf(ys_mx, 0.0f)); const int yhi = (v >= sz - 1) ? sz - 1 : v + 1;
    v = (int)floorf(fmaxf(xs_mn, 0.0f)); const int xlo = (v >= sz - 1) ? sz - 1 : v;
    v = (int)floorf(fmaxf(xs_mx, 0.0f)); const int xhi = (v >= sz - 1) ? sz - 1 : v + 1;
    int ph = yhi - ylo + 1;
    const int pw = xhi - xlo + 1;
    if (pw * ph + 1 > CAP) ph = (CAP - 1) / pw;   // provably never taken; memory-safety net
    const int npc = pw * ph;

    // ---- phase A: 196 sample records, patch-relative offsets ----
    if (t < 196) {
        const int bin = t >> 2, sub = t & 3;
        const int pby = bin / POUT, pbx = bin % POUT;
        const int iy = sub >> 1,   ix = sub & 1;

        const float ys = y0 + ((float)pby + ((float)iy + 0.5f) * 0.5f) * bin_h;
        const float xs = x0 + ((float)pbx + ((float)ix + 0.5f) * 0.5f) * bin_w;

        const bool  vy  = (ys >= -1.0f) && (ys <= (float)sz);
        const float cy  = fmaxf(ys, 0.0f);
        const int   yl0 = (int)floorf(cy);
        const bool  ey  = yl0 >= sz - 1;
        const int   yl  = ey ? sz - 1 : yl0;
        const int   yh  = ey ? sz - 1 : yl0 + 1;
        const float ly  = ey ? 0.0f : cy - (float)yl0;

        const bool  vx  = (xs >= -1.0f) && (xs <= (float)sz);
        const float cx  = fmaxf(xs, 0.0f);
        const int   xl0 = (int)floorf(cx);
        const bool  ex  = xl0 >= sz - 1;
        const int   xl  = ex ? sz - 1 : xl0;
        const float lx  = ex ? 0.0f : cx - (float)xl0;

        const float hy = 1.0f - ly, hx = 1.0f - lx;
        const float m  = (vy && vx) ? 0.25f : 0.0f;   // fold subsample mean
        const float w00 = hy * hx * m, w01 = hy * lx * m;
        const float w10 = ly * hx * m, w11 = ly * lx * m;

        __half2 p01 = __floats2half2_rn(w00, w01);
        __half2 p23 = __floats2half2_rn(w10, w11);

        // +1 x-tap is read as offset+1: at xl==x_max we provably have ex
        // (weight 0), so the stray read stays <= npc (zero-filled cell).
        int4 rec;
        rec.x = (yl - ylo) * pw + (xl - xlo);
        rec.y = *reinterpret_cast<const int*>(&p01);
        rec.z = *reinterpret_cast<const int*>(&p23);
        rec.w = (yh - ylo) * pw + (xl - xlo);
        sRec[t] = rec;
    }

    // ---- loader: 8 channel-groups x 32 lanes, coalesced row reads ----
    const int g    = t >> 5;
    const int lane = t & 31;
    const float* gbase = feat + (size_t)(b * NCH) * HW + ylo * sz + xlo;

    auto load_chunk = [&](int cc) {
        const float* src = gbase + (size_t)(cc * CHK + g) * HW;
        float* dst = &sPatch[g][0];
        for (int py = 0; py < ph; ++py) {
            const float* srow = src + py * sz;
            float* drow = dst + py * pw;
            for (int q = lane; q < pw; q += 32) drow[q] = srow[q];
        }
        if (lane == 0) dst[npc] = 0.0f;   // sink cell for weight-0 edge taps
    };

    load_chunk(0);
    __syncthreads();

    // ---- preload this thread's records into registers (chunk-invariant) ----
    const int  chL  = t & 7;
    const int  bin0 = t >> 3;            // pass-A bin 0..31
    const bool act1 = (t < 136);         // pass-B bins 32..48 (17*8=136 items)
    const float* P = &sPatch[chL][0];

    int oxA[4], oyA[4], oxB[4], oyB[4];
    float2 wxA[4], wyA[4], wxB[4], wyB[4];
    #pragma unroll
    for (int s = 0; s < 4; ++s) {
        const int4 r = sRec[(bin0 << 2) | s];
        oxA[s] = r.x; oyA[s] = r.w;
        wxA[s] = __half22float2(*reinterpret_cast<const __half2*>(&r.y));
        wyA[s] = __half22float2(*reinterpret_cast<const __half2*>(&r.z));
    }
    if (act1) {
        #pragma unroll
        for (int s = 0; s < 4; ++s) {
            const int4 r = sRec[((bin0 + 32) << 2) | s];
            oxB[s] = r.x; oyB[s] = r.w;
            wxB[s] = __half22float2(*reinterpret_cast<const __half2*>(&r.y));
            wyB[s] = __half22float2(*reinterpret_cast<const __half2*>(&r.z));
        }
    }
    const int stA = chL * 49 + bin0;
    float* obase = out + (size_t)n * (NCH * POUT * POUT);

    // ---- main loop: compute chunk cc | drain results + prefetch cc+1 ----
    #pragma unroll 1
    for (int cc = 0; cc < NCHUNK; ++cc) {
        float a0 = 0.0f;
        #pragma unroll
        for (int s = 0; s < 4; ++s)
            a0 += wxA[s].x * P[oxA[s]] + wxA[s].y * P[oxA[s] + 1]
                + wyA[s].x * P[oyA[s]] + wyA[s].y * P[oyA[s] + 1];
        sStage[stA] = a0;
        if (act1) {
            float a1 = 0.0f;
            #pragma unroll
            for (int s = 0; s < 4; ++s)
                a1 += wxB[s].x * P[oxB[s]] + wxB[s].y * P[oxB[s] + 1]
                    + wyB[s].x * P[oyB[s]] + wyB[s].y * P[oyB[s] + 1];
            sStage[stA + 32] = a1;
        }
        __syncthreads();
        // 392 floats -> global, coalesced float2 by 196 threads
        if (t < 196) {
            float2* d2 = (float2*)(obase + cc * (CHK * 49));
            d2[t] = ((const float2*)sStage)[t];
        }
        if (cc + 1 < NCHUNK) load_chunk(cc + 1);
        __syncthreads();
    }
}

extern "C" void kernel_launch(void* const* d_in, const int* in_sizes, int n_in,
                              void* d_out, int out_size, void* d_ws, size_t ws_size,
                              hipStream_t stream) {
    const float* f0 = (const float*)d_in[0];
    const float* f1 = (const float*)d_in[1];
    const float* f2 = (const float*)d_in[2];
    const float* f3 = (const float*)d_in[3];
    const float* props = (const float*)d_in[4];
    float* out = (float*)d_out;

    const int N = in_sizes[4] / 4;                 // 1024 boxes
    const int B = in_sizes[0] / (NCH * 200 * 200); // 2 images
    const int boxes_per_img = N / B;               // 512

    roi_patch_kernel<<<N, 256, 0, stream>>>(f0, f1, f2, f3, props, out, boxes_per_img);
}

// Round 2
// 233.125 us; speedup vs baseline: 8.1776x; 8.1776x over previous
//
#include <hip/hip_runtime.h>
#include <hip/hip_fp16.h>
#include <math.h>

#define POUT 7
#define NCH 256

// ---------------- level geometry (elements) ----------------
#define HW0 40000
#define HW1 10000
#define HW2 2500
#define HW3 625
#define WS_OFF0 0
#define WS_OFF1 (2*NCH*HW0)
#define WS_OFF2 (WS_OFF1 + 2*NCH*HW1)
#define WS_OFF3 (WS_OFF2 + 2*NCH*HW2)
#define WS_ELEMS (WS_OFF3 + 2*NCH*HW3)      // 27,200,000 floats = 108.8 MB
// +256 floats slack: o01/o11 = o00/o10 + 256 may read 1 element-row past the
// last image (weight is exactly 0 there; zeroed via hipMemsetAsync below).
#define WS_NEED  ((size_t)(WS_ELEMS + 256) * sizeof(float))

// ---------------- fused NCHW -> NHWC transpose, all 4 levels ----------------
// Tile: 112 positions x 128 channels. c-major LDS, odd stride 113:
//  - global reads: 448 B contiguous per channel-row (vs 256 B before)
//  - global writes: 512 B contiguous per position (128 ch x 4 B)
//  - LDS read-out: stride 113 (odd) -> 2-way banks, conflict-free
// One launch for all levels: level-0 tiles first, small levels fill idle CUs.
#define TP 112
#define TC 128
#define TSTR 113
#define NT0 ((HW0 + TP - 1) / TP)   // 358
#define NT1 ((HW1 + TP - 1) / TP)   // 90
#define NT2 ((HW2 + TP - 1) / TP)   // 23
#define NT3 ((HW3 + TP - 1) / TP)   // 6

__global__ __launch_bounds__(512) void transpose_fused_kernel(
    const float* __restrict__ f0, const float* __restrict__ f1,
    const float* __restrict__ f2, const float* __restrict__ f3,
    float* __restrict__ ws, int B)
{
    __shared__ float tile[TC * TSTR];   // 57,856 B -> 2 blocks/CU

    int id = blockIdx.x;
    const int s0 = NT0 * 2 * B, s1 = NT1 * 2 * B, s2 = NT2 * 2 * B;
    const float* src; int HW, nt; size_t woff;
    if (id < s0)                 { src = f0; HW = HW0; nt = NT0; woff = WS_OFF0; }
    else if (id - s0 < s1)       { id -= s0; src = f1; HW = HW1; nt = NT1; woff = WS_OFF1; }
    else if (id - s0 - s1 < s2)  { id -= s0 + s1; src = f2; HW = HW2; nt = NT2; woff = WS_OFF2; }
    else                         { id -= s0 + s1 + s2; src = f3; HW = HW3; nt = NT3; woff = WS_OFF3; }

    const int tl   = id % nt;           // position tile (fast axis: write locality)
    const int rest = id / nt;
    const int ch   = rest & 1;          // channel half (0/1)
    const int bb   = rest >> 1;         // batch
    const int p0   = tl * TP;
    const int c0   = ch * TC;
    const int pn   = min(TP, HW - p0);  // valid positions in this tile

    const int t = threadIdx.x;
    const float* sbase = src + ((size_t)(bb * NCH + c0)) * HW + p0;

    // ---- in: 128 channel-rows x 28 float4, linear thread mapping ----
    const int nf4 = TC * (TP / 4);      // 3584
    if (pn == TP) {
        for (int i = t; i < nf4; i += 512) {
            const int c  = i / (TP / 4);
            const int p4 = i - c * (TP / 4);
            const float4 v = *(const float4*)&sbase[(size_t)c * HW + p4 * 4];
            float* d = &tile[c * TSTR + p4 * 4];   // 4B-aligned only: scalar stores
            d[0] = v.x; d[1] = v.y; d[2] = v.z; d[3] = v.w;
        }
    } else {
        for (int i = t; i < nf4; i += 512) {
            const int c  = i / (TP / 4);
            const int pb = (i - c * (TP / 4)) * 4;
            float v[4] = {0.f, 0.f, 0.f, 0.f};
            for (int k = 0; k < 4; ++k)
                if (pb + k < pn) v[k] = sbase[(size_t)c * HW + pb + k];
            float* d = &tile[c * TSTR + pb];
            d[0] = v[0]; d[1] = v[1]; d[2] = v[2]; d[3] = v[3];
        }
    }
    __syncthreads();

    // ---- out: pn position-rows x 128 ch, float2 stores (512 B/wave) ----
    float* dbase = ws + woff + ((size_t)bb * HW + p0) * NCH + c0;
    const int nf2 = (TC / 2) * TP;      // 7168
    for (int i = t; i < nf2; i += 512) {
        const int p  = i >> 6;          // / (TC/2)
        const int c2 = i & 63;
        if (p < pn) {
            float2 w;
            w.x = tile[(2 * c2    ) * TSTR + p];
            w.y = tile[(2 * c2 + 1) * TSTR + p];
            *(float2*)&dbase[(size_t)p * NCH + 2 * c2] = w;
        }
    }
}

// ---------------- uniform 196-sample gather from NHWC (verified, 59 us) ------
__global__ __launch_bounds__(256, 4) void roi_gather_kernel(
    const float* __restrict__ ws, const float* __restrict__ props,
    float* __restrict__ out, int boxes_per_img)
{
    __shared__ int4  sRec[196];
    __shared__ float sStage[64 * 49];

    const int n = blockIdx.x;
    const int t = threadIdx.x;
    const int b = n / boxes_per_img;

    const float4 box = ((const float4*)props)[n];
    const float area = (box.z - box.x) * (box.w - box.y);
    float lvlf = floorf(4.0f + log2f(sqrtf(area) / 224.0f + 1e-6f));
    lvlf = fminf(fmaxf(lvlf, 2.0f), 5.0f) - 2.0f;
    const int l = (int)lvlf;

    int sz; size_t lvl_off;
    if      (l == 0) { sz = 200; lvl_off = WS_OFF0; }
    else if (l == 1) { sz = 100; lvl_off = WS_OFF1; }
    else if (l == 2) { sz = 50;  lvl_off = WS_OFF2; }
    else             { sz = 25;  lvl_off = WS_OFF3; }
    const int HW = sz * sz;
    const float scale = 0.25f / (float)(1 << l);

    if (t < 196) {
        const int bin = t >> 2, sub = t & 3;
        const int ph = bin / POUT, pw = bin % POUT;
        const int iy = sub >> 1,  ix = sub & 1;

        const float x0 = box.x * scale, y0 = box.y * scale;
        const float x1 = box.z * scale, y1 = box.w * scale;
        const float bin_w = fmaxf(x1 - x0, 1.0f) / (float)POUT;
        const float bin_h = fmaxf(y1 - y0, 1.0f) / (float)POUT;

        const float ys = y0 + ((float)ph + ((float)iy + 0.5f) * 0.5f) * bin_h;
        const float xs = x0 + ((float)pw + ((float)ix + 0.5f) * 0.5f) * bin_w;

        const bool  vy  = (ys >= -1.0f) && (ys <= (float)sz);
        const float cy  = fmaxf(ys, 0.0f);
        const int   yl0 = (int)floorf(cy);
        const bool  ey  = yl0 >= sz - 1;
        const int   yl  = ey ? sz - 1 : yl0;
        const int   yh  = ey ? sz - 1 : yl0 + 1;
        const float ly  = ey ? 0.0f : cy - (float)yl0;

        const bool  vx  = (xs >= -1.0f) && (xs <= (float)sz);
        const float cx  = fmaxf(xs, 0.0f);
        const int   xl0 = (int)floorf(cx);
        const bool  ex  = xl0 >= sz - 1;
        const int   xl  = ex ? sz - 1 : xl0;
        const float lx  = ex ? 0.0f : cx - (float)xl0;

        const float hy = 1.0f - ly, hx = 1.0f - lx;
        const float m  = (vy && vx) ? 0.25f : 0.0f;   // fold subsample mean
        const float w00 = hy * hx * m, w01 = hy * lx * m;
        const float w10 = ly * hx * m, w11 = ly * lx * m;

        __half2 p01 = __floats2half2_rn(w00, w01);
        __half2 p23 = __floats2half2_rn(w10, w11);

        int4 rec;
        rec.x = (yl * sz + xl) * NCH;                 // o00 (in-bounds)
        rec.y = *reinterpret_cast<const int*>(&p01);
        rec.z = *reinterpret_cast<const int*>(&p23);
        rec.w = (yh * sz + xl) * NCH;                 // o10 (in-bounds)
        sRec[t] = rec;
    }
    __syncthreads();

    const float* fb = ws + lvl_off + (size_t)b * (size_t)HW * NCH + t;

    float acc[49];
    #pragma unroll
    for (int bin = 0; bin < 49; ++bin) {
        float a = 0.0f;
        #pragma unroll
        for (int sub = 0; sub < 4; ++sub) {
            const int4 rec = sRec[bin * 4 + sub];
            const __half2 h01 = *reinterpret_cast<const __half2*>(&rec.y);
            const __half2 h23 = *reinterpret_cast<const __half2*>(&rec.z);
            const float2 w01 = __half22float2(h01);
            const float2 w23 = __half22float2(h23);
            a += w01.x * fb[rec.x] + w01.y * fb[rec.x + NCH]
               + w23.x * fb[rec.w] + w23.y * fb[rec.w + NCH];
        }
        acc[bin] = a;
    }

    // ---- staged coalesced stores: 64 channels x 49 bins per round ----
    __syncthreads();
    float* obase = out + (size_t)n * (NCH * 49);
    #pragma unroll
    for (int r = 0; r < 4; ++r) {
        if ((t >> 6) == r) {
            #pragma unroll
            for (int i = 0; i < 49; ++i) sStage[(t & 63) * 49 + i] = acc[i];
        }
        __syncthreads();
        float4* d4 = (float4*)(obase + r * (64 * 49));
        const float4* s4 = (const float4*)sStage;
        for (int i = t; i < 64 * 49 / 4; i += 256) d4[i] = s4[i];
        __syncthreads();
    }
}

// ---------------- fallback (round-1 NCHW kernel) ----------------
__global__ __launch_bounds__(256, 4) void roi_align_nchw_kernel(
    const float* __restrict__ f0, const float* __restrict__ f1,
    const float* __restrict__ f2, const float* __restrict__ f3,
    const float* __restrict__ props, float* __restrict__ out, int boxes_per_img)
{
    const int n = blockIdx.x;
    const int t = threadIdx.x;
    if (t >= 196) return;
    const int bin = t >> 2, q = t & 3;
    const int ph = bin / POUT, pw = bin % POUT;
    const int iy = q >> 1,    ix = q & 1;
    const int b = n / boxes_per_img;

    const float4 box = ((const float4*)props)[n];
    const float area = (box.z - box.x) * (box.w - box.y);
    float lvlf = floorf(4.0f + log2f(sqrtf(area) / 224.0f + 1e-6f));
    lvlf = fminf(fmaxf(lvlf, 2.0f), 5.0f) - 2.0f;
    const int l = (int)lvlf;

    const float* feat; int sz;
    if      (l == 0) { feat = f0; sz = 200; }
    else if (l == 1) { feat = f1; sz = 100; }
    else if (l == 2) { feat = f2; sz = 50;  }
    else             { feat = f3; sz = 25;  }
    const float scale = 0.25f / (float)(1 << l);

    const float x0 = box.x * scale, y0 = box.y * scale;
    const float x1 = box.z * scale, y1 = box.w * scale;
    const float bin_w = fmaxf(x1 - x0, 1.0f) / (float)POUT;
    const float bin_h = fmaxf(y1 - y0, 1.0f) / (float)POUT;
    const float ysamp = y0 + ((float)ph + ((float)iy + 0.5f) * 0.5f) * bin_h;
    const float xsamp = x0 + ((float)pw + ((float)ix + 0.5f) * 0.5f) * bin_w;

    const bool  vy  = (ysamp >= -1.0f) && (ysamp <= (float)sz);
    const float cy  = fmaxf(ysamp, 0.0f);
    const int   yl0 = (int)floorf(cy);
    const bool  ey  = yl0 >= sz - 1;
    const int   yl  = ey ? sz - 1 : yl0;
    const int   yh  = ey ? sz - 1 : yl0 + 1;
    const float ly  = ey ? 0.0f : cy - (float)yl0;
    const bool  vx  = (xsamp >= -1.0f) && (xsamp <= (float)sz);
    const float cx  = fmaxf(xsamp, 0.0f);
    const int   xl0 = (int)floorf(cx);
    const bool  ex  = xl0 >= sz - 1;
    const int   xl  = ex ? sz - 1 : xl0;
    const int   xh  = ex ? sz - 1 : xl0 + 1;
    const float lx  = ex ? 0.0f : cx - (float)xl0;

    const float hy = 1.0f - ly, hx = 1.0f - lx;
    const float m  = (vy && vx) ? 1.0f : 0.0f;
    const float w00 = hy * hx * m, w01 = hy * lx * m;
    const float w10 = ly * hx * m, w11 = ly * lx * m;

    const int HW = sz * sz;
    const float* base = feat + (size_t)b * NCH * HW;
    int o00 = yl * sz + xl, o01 = yl * sz + xh;
    int o10 = yh * sz + xl, o11 = yh * sz + xh;
    float* op = out + (size_t)n * NCH * (POUT * POUT) + bin;

    #pragma unroll 4
    for (int cch = 0; cch < NCH; ++cch) {
        float v = w00 * base[o00] + w01 * base[o01]
                + w10 * base[o10] + w11 * base[o11];
        v += __shfl_xor(v, 1);
        v += __shfl_xor(v, 2);
        if (q == 0) op[cch * (POUT * POUT)] = v * 0.25f;
        o00 += HW; o01 += HW; o10 += HW; o11 += HW;
    }
}

extern "C" void kernel_launch(void* const* d_in, const int* in_sizes, int n_in,
                              void* d_out, int out_size, void* d_ws, size_t ws_size,
                              hipStream_t stream) {
    const float* f0 = (const float*)d_in[0];
    const float* f1 = (const float*)d_in[1];
    const float* f2 = (const float*)d_in[2];
    const float* f3 = (const float*)d_in[3];
    const float* props = (const float*)d_in[4];
    float* out = (float*)d_out;

    const int N = in_sizes[4] / 4;                 // 1024 boxes
    const int B = in_sizes[0] / (NCH * HW0);       // 2 images
    const int boxes_per_img = N / B;               // 512

    if (ws_size >= WS_NEED && B == 2) {
        float* wsf = (float*)d_ws;
        // zero the +256-float slack so weight-0 edge taps never read NaN
        hipMemsetAsync(wsf + WS_ELEMS, 0, 256 * sizeof(float), stream);
        const int nblk = (NT0 + NT1 + NT2 + NT3) * 2 * B;   // 1908
        transpose_fused_kernel<<<nblk, 512, 0, stream>>>(f0, f1, f2, f3, wsf, B);
        roi_gather_kernel<<<N, 256, 0, stream>>>(wsf, props, out, boxes_per_img);
    } else {
        roi_align_nchw_kernel<<<N, 256, 0, stream>>>(f0, f1, f2, f3, props, out, boxes_per_img);
    }
}

// Round 3
// 223.488 us; speedup vs baseline: 8.5302x; 1.0431x over previous
//
#include <hip/hip_runtime.h>
#include <hip/hip_fp16.h>
#include <math.h>

#define POUT 7
#define NCH 256

// ---------------- level geometry (elements) ----------------
#define HW0 40000
#define HW1 10000
#define HW2 2500
#define HW3 625
#define WS_OFF0 0
#define WS_OFF1 (2*NCH*HW0)
#define WS_OFF2 (WS_OFF1 + 2*NCH*HW1)
#define WS_OFF3 (WS_OFF2 + 2*NCH*HW2)
#define WS_ELEMS (WS_OFF3 + 2*NCH*HW3)      // 27,200,000 floats = 108.8 MB
// +256 floats slack (zeroed by transpose block 0): o01/o11 = o00/o10 + 256 may
// read one element-row past the last image (weight exactly 0 there).
// +1024 ints: sorted box permutation (written by transpose block 0).
#define WS_PERM_OFF (WS_ELEMS + 256)
#define WS_NEED  ((size_t)(WS_PERM_OFF + 1024) * sizeof(float))

// ---------------- fused NCHW -> NHWC transpose, all 4 levels ----------------
// Tile: 56 positions x 128 channels, 512 threads, LDS 29.2 KB -> 4 blocks/CU
// (100% occupancy cap; was 50%). Channel-half is the FASTEST block axis so
// sibling blocks write complementary 512 B chunks of the same position rows
// concurrently -> full DRAM lines (was 512B-used/512B-skipped at ~50% eff).
// LDS is channel-pair interleaved: ch c, pos p -> tile[(c>>1)*RS + 2p + (c&1)],
// RS=114 (2*odd) makes the read-out float2 a conflict-free b64 (each bank
// serves exactly 4 b32 per wave).
#define TP 56
#define RS 114
#define NT0 ((HW0 + TP - 1) / TP)   // 715
#define NT1 ((HW1 + TP - 1) / TP)   // 179
#define NT2 ((HW2 + TP - 1) / TP)   // 45
#define NT3 ((HW3 + TP - 1) / TP)   // 12
#define NBLK ((NT0 + NT1 + NT2 + NT3) * 4)   // 2 ch-halves x 2 images = 3804

__global__ __launch_bounds__(512, 8) void transpose_fused_kernel(
    const float* __restrict__ f0, const float* __restrict__ f1,
    const float* __restrict__ f2, const float* __restrict__ f3,
    float* __restrict__ ws, const float* __restrict__ props,
    int boxes_per_img, int N)
{
    __shared__ float tile[64 * RS];   // 29,184 B

    const int gid = blockIdx.x;
    int id = gid;
    const float* src; int HW, nt; size_t woff;
    if (id < NT0 * 4)                        { src = f0; HW = HW0; nt = NT0; woff = WS_OFF0; }
    else if ((id -= NT0 * 4) < NT1 * 4)      { src = f1; HW = HW1; nt = NT1; woff = WS_OFF1; }
    else if ((id -= NT1 * 4) < NT2 * 4)      { src = f2; HW = HW2; nt = NT2; woff = WS_OFF2; }
    else { id -= NT2 * 4;                      src = f3; HW = HW3; nt = NT3; woff = WS_OFF3; }

    const int ch = id & 1;                  // fastest: adjacent blocks = complementary halves
    const int tl = (id >> 1) % nt;
    const int bb = (id >> 1) / nt;
    const int p0 = tl * TP;
    const int pn = min(TP, HW - p0);
    const int c0 = ch * 128;
    const int t  = threadIdx.x;

    const float* sbase = src + ((size_t)(bb * NCH + c0)) * HW + p0;

    // ---- in: 128 channel-rows x 14 float4 (224 B contiguous per row) ----
    if (pn == TP) {
        for (int i = t; i < 128 * (TP / 4); i += 512) {
            const int c  = i / (TP / 4);
            const int p4 = i - c * (TP / 4);
            const float4 v = *(const float4*)&sbase[(size_t)c * HW + p4 * 4];
            float* d = &tile[(c >> 1) * RS + (c & 1) + p4 * 8];
            d[0] = v.x; d[2] = v.y; d[4] = v.z; d[6] = v.w;
        }
    } else {
        for (int i = t; i < 128 * (TP / 4); i += 512) {
            const int c  = i / (TP / 4);
            const int pb = (i - c * (TP / 4)) * 4;
            float vv[4];
            #pragma unroll
            for (int k = 0; k < 4; ++k)
                vv[k] = (pb + k < pn) ? sbase[(size_t)c * HW + pb + k] : 0.0f;
            float* d = &tile[(c >> 1) * RS + (c & 1) + pb * 2];
            d[0] = vv[0]; d[2] = vv[1]; d[4] = vv[2]; d[6] = vv[3];
        }
    }
    __syncthreads();

    // ---- out: pn position-rows x 64 float2 (512 B/wave, sibling block fills
    //      the other 512 B of the same 1 KB row) ----
    float* dbase = ws + woff + ((size_t)bb * HW + p0) * NCH + c0;
    for (int i = t; i < 64 * TP; i += 512) {
        const int c2 = i & 63, p = i >> 6;
        if (p < pn) {
            const float2 v = *(const float2*)&tile[c2 * RS + 2 * p];
            *(float2*)&dbase[(size_t)p * NCH + 2 * c2] = v;
        }
    }

    // ---- block 0 extras (hidden under the other 3803 blocks):
    //      zero the slack row + bitonic-sort boxes by (img, lvl, y, x) ----
    if (gid == 0) {
        __syncthreads();                     // LDS reuse: out-phase reads done
        unsigned* keys = (unsigned*)tile;
        if (N == 1024) {
            for (int i = t; i < 1024; i += 512) {
                const float4 box = ((const float4*)props)[i];
                const float area = (box.z - box.x) * (box.w - box.y);
                float lvlf = floorf(4.0f + log2f(sqrtf(area) / 224.0f + 1e-6f));
                lvlf = fminf(fmaxf(lvlf, 2.0f), 5.0f) - 2.0f;
                const int l = (int)lvlf;
                const float sc = 0.25f / (float)(1 << l);
                int yc = (int)(0.5f * (box.y + box.w) * sc);
                int xc = (int)(0.5f * (box.x + box.z) * sc);
                yc = yc < 0 ? 0 : (yc > 255 ? 255 : yc);
                xc = xc < 0 ? 0 : (xc > 255 ? 255 : xc);
                const unsigned hi = (unsigned)((i / boxes_per_img) * 4 + l);
                keys[i] = (((hi << 8 | (unsigned)yc) << 8 | (unsigned)xc) << 10) | (unsigned)i;
            }
            for (int size = 2; size <= 1024; size <<= 1)
                for (int stride = size >> 1; stride > 0; stride >>= 1) {
                    __syncthreads();
                    const int lo = t & (stride - 1);
                    const int k  = ((t ^ lo) << 1) | lo;
                    const unsigned a = keys[k], b2 = keys[k + stride];
                    if ((a > b2) == ((k & size) == 0)) { keys[k] = b2; keys[k + stride] = a; }
                }
            __syncthreads();
            int* perm = (int*)(ws + WS_PERM_OFF);
            for (int i = t; i < 1024; i += 512) perm[i] = (int)(keys[i] & 1023u);
        }
        if (t < 256) ws[WS_ELEMS + t] = 0.0f;
    }
}

// ---------------- uniform 196-sample gather from NHWC ----------------
// Box order comes from the sorted perm (L2 locality); XCD-chunked mapping so
// each XCD's private L2 sees one contiguous (img,lvl,y,x)-sorted range.
__global__ __launch_bounds__(256, 4) void roi_gather_kernel(
    const float* __restrict__ ws, const float* __restrict__ props,
    float* __restrict__ out, int boxes_per_img)
{
    __shared__ int4  sRec[196];
    __shared__ float sStage[64 * 49];

    const int* perm = (const int*)(ws + WS_PERM_OFF);
    const int n = perm[(blockIdx.x & 7) * 128 + (blockIdx.x >> 3)];
    const int t = threadIdx.x;
    const int b = n / boxes_per_img;

    const float4 box = ((const float4*)props)[n];
    const float area = (box.z - box.x) * (box.w - box.y);
    float lvlf = floorf(4.0f + log2f(sqrtf(area) / 224.0f + 1e-6f));
    lvlf = fminf(fmaxf(lvlf, 2.0f), 5.0f) - 2.0f;
    const int l = (int)lvlf;

    int sz; size_t lvl_off;
    if      (l == 0) { sz = 200; lvl_off = WS_OFF0; }
    else if (l == 1) { sz = 100; lvl_off = WS_OFF1; }
    else if (l == 2) { sz = 50;  lvl_off = WS_OFF2; }
    else             { sz = 25;  lvl_off = WS_OFF3; }
    const int HW = sz * sz;
    const float scale = 0.25f / (float)(1 << l);

    if (t < 196) {
        const int bin = t >> 2, sub = t & 3;
        const int ph = bin / POUT, pw = bin % POUT;
        const int iy = sub >> 1,  ix = sub & 1;

        const float x0 = box.x * scale, y0 = box.y * scale;
        const float x1 = box.z * scale, y1 = box.w * scale;
        const float bin_w = fmaxf(x1 - x0, 1.0f) / (float)POUT;
        const float bin_h = fmaxf(y1 - y0, 1.0f) / (float)POUT;

        const float ys = y0 + ((float)ph + ((float)iy + 0.5f) * 0.5f) * bin_h;
        const float xs = x0 + ((float)pw + ((float)ix + 0.5f) * 0.5f) * bin_w;

        const bool  vy  = (ys >= -1.0f) && (ys <= (float)sz);
        const float cy  = fmaxf(ys, 0.0f);
        const int   yl0 = (int)floorf(cy);
        const bool  ey  = yl0 >= sz - 1;
        const int   yl  = ey ? sz - 1 : yl0;
        const int   yh  = ey ? sz - 1 : yl0 + 1;
        const float ly  = ey ? 0.0f : cy - (float)yl0;

        const bool  vx  = (xs >= -1.0f) && (xs <= (float)sz);
        const float cx  = fmaxf(xs, 0.0f);
        const int   xl0 = (int)floorf(cx);
        const bool  ex  = xl0 >= sz - 1;
        const int   xl  = ex ? sz - 1 : xl0;
        const float lx  = ex ? 0.0f : cx - (float)xl0;

        const float hy = 1.0f - ly, hx = 1.0f - lx;
        const float m  = (vy && vx) ? 0.25f : 0.0f;   // fold subsample mean
        const float w00 = hy * hx * m, w01 = hy * lx * m;
        const float w10 = ly * hx * m, w11 = ly * lx * m;

        __half2 p01 = __floats2half2_rn(w00, w01);
        __half2 p23 = __floats2half2_rn(w10, w11);

        int4 rec;
        rec.x = (yl * sz + xl) * NCH;                 // o00 (in-bounds)
        rec.y = *reinterpret_cast<const int*>(&p01);
        rec.z = *reinterpret_cast<const int*>(&p23);
        rec.w = (yh * sz + xl) * NCH;                 // o10 (in-bounds)
        sRec[t] = rec;
    }
    __syncthreads();

    const float* fb = ws + lvl_off + (size_t)b * (size_t)HW * NCH + t;

    float acc[49];
    #pragma unroll
    for (int bin = 0; bin < 49; ++bin) {
        float a = 0.0f;
        #pragma unroll
        for (int sub = 0; sub < 4; ++sub) {
            const int4 rec = sRec[bin * 4 + sub];
            const __half2 h01 = *reinterpret_cast<const __half2*>(&rec.y);
            const __half2 h23 = *reinterpret_cast<const __half2*>(&rec.z);
            const float2 w01 = __half22float2(h01);
            const float2 w23 = __half22float2(h23);
            a += w01.x * fb[rec.x] + w01.y * fb[rec.x + NCH]
               + w23.x * fb[rec.w] + w23.y * fb[rec.w + NCH];
        }
        acc[bin] = a;
    }

    // ---- staged coalesced stores: 64 channels x 49 bins per round ----
    __syncthreads();
    float* obase = out + (size_t)n * (NCH * 49);
    #pragma unroll
    for (int r = 0; r < 4; ++r) {
        if ((t >> 6) == r) {
            #pragma unroll
            for (int i = 0; i < 49; ++i) sStage[(t & 63) * 49 + i] = acc[i];
        }
        __syncthreads();
        float4* d4 = (float4*)(obase + r * (64 * 49));
        const float4* s4 = (const float4*)sStage;
        for (int i = t; i < 64 * 49 / 4; i += 256) d4[i] = s4[i];
        __syncthreads();
    }
}

// ---------------- fallback (general shapes, NCHW direct) ----------------
__global__ __launch_bounds__(256, 4) void roi_align_nchw_kernel(
    const float* __restrict__ f0, const float* __restrict__ f1,
    const float* __restrict__ f2, const float* __restrict__ f3,
    const float* __restrict__ props, float* __restrict__ out, int boxes_per_img)
{
    const int n = blockIdx.x;
    const int t = threadIdx.x;
    if (t >= 196) return;
    const int bin = t >> 2, q = t & 3;
    const int ph = bin / POUT, pw = bin % POUT;
    const int iy = q >> 1,    ix = q & 1;
    const int b = n / boxes_per_img;

    const float4 box = ((const float4*)props)[n];
    const float area = (box.z - box.x) * (box.w - box.y);
    float lvlf = floorf(4.0f + log2f(sqrtf(area) / 224.0f + 1e-6f));
    lvlf = fminf(fmaxf(lvlf, 2.0f), 5.0f) - 2.0f;
    const int l = (int)lvlf;

    const float* feat; int sz;
    if      (l == 0) { feat = f0; sz = 200; }
    else if (l == 1) { feat = f1; sz = 100; }
    else if (l == 2) { feat = f2; sz = 50;  }
    else             { feat = f3; sz = 25;  }
    const float scale = 0.25f / (float)(1 << l);

    const float x0 = box.x * scale, y0 = box.y * scale;
    const float x1 = box.z * scale, y1 = box.w * scale;
    const float bin_w = fmaxf(x1 - x0, 1.0f) / (float)POUT;
    const float bin_h = fmaxf(y1 - y0, 1.0f) / (float)POUT;
    const float ysamp = y0 + ((float)ph + ((float)iy + 0.5f) * 0.5f) * bin_h;
    const float xsamp = x0 + ((float)pw + ((float)ix + 0.5f) * 0.5f) * bin_w;

    const bool  vy  = (ysamp >= -1.0f) && (ysamp <= (float)sz);
    const float cy  = fmaxf(ysamp, 0.0f);
    const int   yl0 = (int)floorf(cy);
    const bool  ey  = yl0 >= sz - 1;
    const int   yl  = ey ? sz - 1 : yl0;
    const int   yh  = ey ? sz - 1 : yl0 + 1;
    const float ly  = ey ? 0.0f : cy - (float)yl0;
    const bool  vx  = (xsamp >= -1.0f) && (xsamp <= (float)sz);
    const float cx  = fmaxf(xsamp, 0.0f);
    const int   xl0 = (int)floorf(cx);
    const bool  ex  = xl0 >= sz - 1;
    const int   xl  = ex ? sz - 1 : xl0;
    const int   xh  = ex ? sz - 1 : xl0 + 1;
    const float lx  = ex ? 0.0f : cx - (float)xl0;

    const float hy = 1.0f - ly, hx = 1.0f - lx;
    const float m  = (vy && vx) ? 1.0f : 0.0f;
    const float w00 = hy * hx * m, w01 = hy * lx * m;
    const float w10 = ly * hx * m, w11 = ly * lx * m;

    const int HW = sz * sz;
    const float* base = feat + (size_t)b * NCH * HW;
    int o00 = yl * sz + xl, o01 = yl * sz + xh;
    int o10 = yh * sz + xl, o11 = yh * sz + xh;
    float* op = out + (size_t)n * NCH * (POUT * POUT) + bin;

    #pragma unroll 4
    for (int cch = 0; cch < NCH; ++cch) {
        float v = w00 * base[o00] + w01 * base[o01]
                + w10 * base[o10] + w11 * base[o11];
        v += __shfl_xor(v, 1);
        v += __shfl_xor(v, 2);
        if (q == 0) op[cch * (POUT * POUT)] = v * 0.25f;
        o00 += HW; o01 += HW; o10 += HW; o11 += HW;
    }
}

extern "C" void kernel_launch(void* const* d_in, const int* in_sizes, int n_in,
                              void* d_out, int out_size, void* d_ws, size_t ws_size,
                              hipStream_t stream) {
    const float* f0 = (const float*)d_in[0];
    const float* f1 = (const float*)d_in[1];
    const float* f2 = (const float*)d_in[2];
    const float* f3 = (const float*)d_in[3];
    const float* props = (const float*)d_in[4];
    float* out = (float*)d_out;

    const int N = in_sizes[4] / 4;                 // 1024 boxes
    const int B = in_sizes[0] / (NCH * HW0);       // 2 images
    const int boxes_per_img = N / B;               // 512

    if (ws_size >= WS_NEED && B == 2 && N == 1024) {
        float* wsf = (float*)d_ws;
        transpose_fused_kernel<<<NBLK, 512, 0, stream>>>(f0, f1, f2, f3, wsf,
                                                         props, boxes_per_img, N);
        roi_gather_kernel<<<N, 256, 0, stream>>>(wsf, props, out, boxes_per_img);
    } else {
        roi_align_nchw_kernel<<<N, 256, 0, stream>>>(f0, f1, f2, f3, props, out, boxes_per_img);
    }
}

// Round 4
// 192.028 us; speedup vs baseline: 9.9277x; 1.1638x over previous
//
#include <hip/hip_runtime.h>
#include <hip/hip_fp16.h>
#include <math.h>

#define POUT 7
#define NCH 256

typedef float v4f __attribute__((ext_vector_type(4)));

// ---------------- level geometry (elements == half-elements of ws) ----------
#define HW0 40000
#define HW1 10000
#define HW2 2500
#define HW3 625
#define WS_OFF0 0
#define WS_OFF1 (2*NCH*HW0)
#define WS_OFF2 (WS_OFF1 + 2*NCH*HW1)
#define WS_OFF3 (WS_OFF2 + 2*NCH*HW2)
#define WS_ELEMS (WS_OFF3 + 2*NCH*HW3)      // 27,200,000 halves = 54.4 MB
// +512 halves slack (zeroed by transpose block 0): the unconditional +NCH
// tap read may touch <=256 halves past the last image (weight exactly 0).
#define WS_SLACK 512
#define WS_PERM_BYTE ((size_t)(WS_ELEMS + WS_SLACK) * 2)
#define WS_NEED (WS_PERM_BYTE + 1024 * sizeof(int))

// ---------------- fused NCHW(f32) -> NHWC(fp16) transpose, all 4 levels -----
// 56 pos x 128 ch tiles, 512 thr, LDS 29.2 KB. ch-half fastest block axis so
// sibling blocks write complementary 256 B chunks of the same 512 B position
// row. Feature reads are NON-TEMPORAL (read-once; keep L3 for the ws so the
// gather hits L3). Block 0 additionally zeroes the ws slack and bitonic-sorts
// boxes by (img,lvl,y,x) -> perm (n | l<<10 | img<<12) for gather L2 locality.
#define TP 56
#define RS 114
#define NT0 ((HW0 + TP - 1) / TP)   // 715
#define NT1 ((HW1 + TP - 1) / TP)   // 179
#define NT2 ((HW2 + TP - 1) / TP)   // 45
#define NT3 ((HW3 + TP - 1) / TP)   // 12
#define NBLK ((NT0 + NT1 + NT2 + NT3) * 4)   // 3804

__global__ __launch_bounds__(512, 8) void transpose_fused_kernel(
    const float* __restrict__ f0, const float* __restrict__ f1,
    const float* __restrict__ f2, const float* __restrict__ f3,
    __half* __restrict__ ws, const float* __restrict__ props,
    int boxes_per_img, int N)
{
    __shared__ float tile[64 * RS];   // 29,184 B

    const int gid = blockIdx.x;
    int id = gid;
    const float* src; int HW, nt; size_t woff;
    if (id < NT0 * 4)                        { src = f0; HW = HW0; nt = NT0; woff = WS_OFF0; }
    else if ((id -= NT0 * 4) < NT1 * 4)      { src = f1; HW = HW1; nt = NT1; woff = WS_OFF1; }
    else if ((id -= NT1 * 4) < NT2 * 4)      { src = f2; HW = HW2; nt = NT2; woff = WS_OFF2; }
    else { id -= NT2 * 4;                      src = f3; HW = HW3; nt = NT3; woff = WS_OFF3; }

    const int ch = id & 1;                  // fastest: complementary row halves
    const int tl = (id >> 1) % nt;
    const int bb = (id >> 1) / nt;
    const int p0 = tl * TP;
    const int pn = min(TP, HW - p0);
    const int c0 = ch * 128;
    const int t  = threadIdx.x;

    const float* sbase = src + ((size_t)(bb * NCH + c0)) * HW + p0;

    // ---- in: 128 channel-rows x 14 float4 (224 B contiguous, nt) ----
    if (pn == TP) {
        for (int i = t; i < 128 * (TP / 4); i += 512) {
            const int c  = i / (TP / 4);
            const int p4 = i - c * (TP / 4);
            const v4f v = __builtin_nontemporal_load(
                (const v4f*)&sbase[(size_t)c * HW + p4 * 4]);
            float* d = &tile[(c >> 1) * RS + (c & 1) + p4 * 8];
            d[0] = v[0]; d[2] = v[1]; d[4] = v[2]; d[6] = v[3];
        }
    } else {
        for (int i = t; i < 128 * (TP / 4); i += 512) {
            const int c  = i / (TP / 4);
            const int pb = (i - c * (TP / 4)) * 4;
            float vv[4];
            #pragma unroll
            for (int k = 0; k < 4; ++k)
                vv[k] = (pb + k < pn) ? sbase[(size_t)c * HW + pb + k] : 0.0f;
            float* d = &tile[(c >> 1) * RS + (c & 1) + pb * 2];
            d[0] = vv[0]; d[2] = vv[1]; d[4] = vv[2]; d[6] = vv[3];
        }
    }
    __syncthreads();

    // ---- out: pn rows x 64 half2 (256 B/wave; sibling fills the other half) -
    __half* dbase = ws + woff + ((size_t)bb * HW + p0) * NCH + c0;
    for (int i = t; i < 64 * TP; i += 512) {
        const int c2 = i & 63, p = i >> 6;
        if (p < pn) {
            const float2 v = *(const float2*)&tile[c2 * RS + 2 * p];
            *(__half2*)&dbase[(size_t)p * NCH + 2 * c2] = __floats2half2_rn(v.x, v.y);
        }
    }

    // ---- block 0: zero slack + bitonic sort (hidden under other blocks) ----
    if (gid == 0) {
        __syncthreads();
        unsigned* keys = (unsigned*)tile;
        if (N == 1024) {
            for (int i = t; i < 1024; i += 512) {
                const float4 box = ((const float4*)props)[i];
                const float area = (box.z - box.x) * (box.w - box.y);
                float lvlf = floorf(4.0f + log2f(sqrtf(area) / 224.0f + 1e-6f));
                lvlf = fminf(fmaxf(lvlf, 2.0f), 5.0f) - 2.0f;
                const int l = (int)lvlf;
                const float sc = 0.25f / (float)(1 << l);
                int yc = (int)(0.5f * (box.y + box.w) * sc);
                int xc = (int)(0.5f * (box.x + box.z) * sc);
                yc = yc < 0 ? 0 : (yc > 255 ? 255 : yc);
                xc = xc < 0 ? 0 : (xc > 255 ? 255 : xc);
                const unsigned hi = (unsigned)((i / boxes_per_img) * 4 + l);
                keys[i] = (((hi << 8 | (unsigned)yc) << 8 | (unsigned)xc) << 10) | (unsigned)i;
            }
            for (int size = 2; size <= 1024; size <<= 1)
                for (int stride = size >> 1; stride > 0; stride >>= 1) {
                    __syncthreads();
                    const int lo = t & (stride - 1);
                    const int k  = ((t ^ lo) << 1) | lo;
                    const unsigned a = keys[k], b2 = keys[k + stride];
                    if ((a > b2) == ((k & size) == 0)) { keys[k] = b2; keys[k + stride] = a; }
                }
            __syncthreads();
            int* perm = (int*)((char*)ws + WS_PERM_BYTE);
            for (int i = t; i < 1024; i += 512) {
                const unsigned k = keys[i];
                perm[i] = (int)((k & 1023u) | (((k >> 26) & 3u) << 10) | ((k >> 28) << 12));
            }
        }
        if (t < 256) ((unsigned*)(ws + WS_ELEMS))[t] = 0u;   // 512 halves
    }
}

// ---------------- 196-sample gather from fp16 NHWC, f32 weights -------------
// Thread = (channel-pair c2, bin-half hf). Each thread computes 2 channels x
// 25 bins (halves overlap at bin 24; hf1 stores bins 25..48). Per tap:
// one half2 load (wave = 256 B contiguous). Output staged via LDS, stored nt.
__global__ __launch_bounds__(256, 4) void roi_gather_kernel(
    const __half* __restrict__ ws, const float* __restrict__ props,
    float* __restrict__ out, int boxes_per_img)
{
    __shared__ int2   sOff[196];
    __shared__ float4 sW[196];
    __shared__ __align__(16) float sStage[64 * 49];

    const int* perm = (const int*)((const char*)ws + WS_PERM_BYTE);
    const int pe = perm[(blockIdx.x & 7) * 128 + (blockIdx.x >> 3)];
    const int n = pe & 1023;
    const int l = (pe >> 10) & 3;
    const int b = pe >> 12;
    const int t = threadIdx.x;

    int sz; size_t lvl_off;
    if      (l == 0) { sz = 200; lvl_off = WS_OFF0; }
    else if (l == 1) { sz = 100; lvl_off = WS_OFF1; }
    else if (l == 2) { sz = 50;  lvl_off = WS_OFF2; }
    else             { sz = 25;  lvl_off = WS_OFF3; }
    const int HW = sz * sz;
    const float scale = 0.25f / (float)(1 << l);

    if (t < 196) {
        const float4 box = ((const float4*)props)[n];
        const int bin = t >> 2, sub = t & 3;
        const int ph = bin / POUT, pw = bin % POUT;
        const int iy = sub >> 1,  ix = sub & 1;

        const float x0 = box.x * scale, y0 = box.y * scale;
        const float x1 = box.z * scale, y1 = box.w * scale;
        const float bin_w = fmaxf(x1 - x0, 1.0f) / (float)POUT;
        const float bin_h = fmaxf(y1 - y0, 1.0f) / (float)POUT;

        const float ys = y0 + ((float)ph + ((float)iy + 0.5f) * 0.5f) * bin_h;
        const float xs = x0 + ((float)pw + ((float)ix + 0.5f) * 0.5f) * bin_w;

        const bool  vy  = (ys >= -1.0f) && (ys <= (float)sz);
        const float cy  = fmaxf(ys, 0.0f);
        const int   yl0 = (int)floorf(cy);
        const bool  ey  = yl0 >= sz - 1;
        const int   yl  = ey ? sz - 1 : yl0;
        const int   yh  = ey ? sz - 1 : yl0 + 1;
        const float ly  = ey ? 0.0f : cy - (float)yl0;

        const bool  vx  = (xs >= -1.0f) && (xs <= (float)sz);
        const float cx  = fmaxf(xs, 0.0f);
        const int   xl0 = (int)floorf(cx);
        const bool  ex  = xl0 >= sz - 1;
        const int   xl  = ex ? sz - 1 : xl0;
        const float lx  = ex ? 0.0f : cx - (float)xl0;

        const float hy = 1.0f - ly, hx = 1.0f - lx;
        const float m  = (vy && vx) ? 0.25f : 0.0f;   // fold subsample mean
        sOff[t] = make_int2((yl * sz + xl) * NCH, (yh * sz + xl) * NCH);
        sW[t]   = make_float4(hy * hx * m, hy * lx * m, ly * hx * m, ly * lx * m);
    }
    __syncthreads();

    const int c2 = t & 127;          // channel pair: channels 2c2, 2c2+1
    const int hf = t >> 7;           // bin half
    const int bin0 = hf * 24;        // hf0: bins 0..24, hf1: bins 24..48
    const __half* fb = ws + lvl_off + (size_t)b * (size_t)HW * NCH + 2 * c2;

    float2 acc[25];
    #pragma unroll
    for (int j = 0; j < 25; ++j) { acc[j].x = 0.0f; acc[j].y = 0.0f; }

    #pragma unroll
    for (int j = 0; j < 25; ++j) {
        const int rbase = (bin0 + j) * 4;
        #pragma unroll
        for (int s = 0; s < 4; ++s) {
            const int2   o = sOff[rbase + s];
            const float4 w = sW[rbase + s];
            const float2 v00 = __half22float2(*(const __half2*)&fb[o.x]);
            const float2 v01 = __half22float2(*(const __half2*)&fb[o.x + NCH]);
            const float2 v10 = __half22float2(*(const __half2*)&fb[o.y]);
            const float2 v11 = __half22float2(*(const __half2*)&fb[o.y + NCH]);
            acc[j].x += w.x * v00.x + w.y * v01.x + w.z * v10.x + w.w * v11.x;
            acc[j].y += w.x * v00.y + w.y * v01.y + w.z * v10.y + w.w * v11.y;
        }
    }

    // ---- staged stores: 64 channels x 49 bins per round, nt float4 ----
    __syncthreads();
    float* obase = out + (size_t)n * (NCH * 49);
    #pragma unroll
    for (int r = 0; r < 4; ++r) {
        if ((c2 >> 5) == r) {
            const int lc = (c2 & 31) * 2;
            if (hf == 0) {
                #pragma unroll
                for (int j = 0; j < 25; ++j) {
                    sStage[lc * 49 + j]       = acc[j].x;
                    sStage[(lc + 1) * 49 + j] = acc[j].y;
                }
            } else {
                #pragma unroll
                for (int j = 1; j < 25; ++j) {
                    sStage[lc * 49 + 24 + j]       = acc[j].x;
                    sStage[(lc + 1) * 49 + 24 + j] = acc[j].y;
                }
            }
        }
        __syncthreads();
        v4f* d4 = (v4f*)(obase + r * (64 * 49));
        const v4f* s4 = (const v4f*)sStage;
        for (int i = t; i < 64 * 49 / 4; i += 256)
            __builtin_nontemporal_store(s4[i], &d4[i]);
        __syncthreads();
    }
}

// ---------------- fallback (general shapes, NCHW direct, f32) ---------------
__global__ __launch_bounds__(256, 4) void roi_align_nchw_kernel(
    const float* __restrict__ f0, const float* __restrict__ f1,
    const float* __restrict__ f2, const float* __restrict__ f3,
    const float* __restrict__ props, float* __restrict__ out, int boxes_per_img)
{
    const int n = blockIdx.x;
    const int t = threadIdx.x;
    if (t >= 196) return;
    const int bin = t >> 2, q = t & 3;
    const int ph = bin / POUT, pw = bin % POUT;
    const int iy = q >> 1,    ix = q & 1;
    const int b = n / boxes_per_img;

    const float4 box = ((const float4*)props)[n];
    const float area = (box.z - box.x) * (box.w - box.y);
    float lvlf = floorf(4.0f + log2f(sqrtf(area) / 224.0f + 1e-6f));
    lvlf = fminf(fmaxf(lvlf, 2.0f), 5.0f) - 2.0f;
    const int l = (int)lvlf;

    const float* feat; int sz;
    if      (l == 0) { feat = f0; sz = 200; }
    else if (l == 1) { feat = f1; sz = 100; }
    else if (l == 2) { feat = f2; sz = 50;  }
    else             { feat = f3; sz = 25;  }
    const float scale = 0.25f / (float)(1 << l);

    const float x0 = box.x * scale, y0 = box.y * scale;
    const float x1 = box.z * scale, y1 = box.w * scale;
    const float bin_w = fmaxf(x1 - x0, 1.0f) / (float)POUT;
    const float bin_h = fmaxf(y1 - y0, 1.0f) / (float)POUT;
    const float ysamp = y0 + ((float)ph + ((float)iy + 0.5f) * 0.5f) * bin_h;
    const float xsamp = x0 + ((float)pw + ((float)ix + 0.5f) * 0.5f) * bin_w;

    const bool  vy  = (ysamp >= -1.0f) && (ysamp <= (float)sz);
    const float cy  = fmaxf(ysamp, 0.0f);
    const int   yl0 = (int)floorf(cy);
    const bool  ey  = yl0 >= sz - 1;
    const int   yl  = ey ? sz - 1 : yl0;
    const int   yh  = ey ? sz - 1 : yl0 + 1;
    const float ly  = ey ? 0.0f : cy - (float)yl0;
    const bool  vx  = (xsamp >= -1.0f) && (xsamp <= (float)sz);
    const float cx  = fmaxf(xsamp, 0.0f);
    const int   xl0 = (int)floorf(cx);
    const bool  ex  = xl0 >= sz - 1;
    const int   xl  = ex ? sz - 1 : xl0;
    const int   xh  = ex ? sz - 1 : xl0 + 1;
    const float lx  = ex ? 0.0f : cx - (float)xl0;

    const float hy = 1.0f - ly, hx = 1.0f - lx;
    const float m  = (vy && vx) ? 1.0f : 0.0f;
    const float w00 = hy * hx * m, w01 = hy * lx * m;
    const float w10 = ly * hx * m, w11 = ly * lx * m;

    const int HW = sz * sz;
    const float* base = feat + (size_t)b * NCH * HW;
    int o00 = yl * sz + xl, o01 = yl * sz + xh;
    int o10 = yh * sz + xl, o11 = yh * sz + xh;
    float* op = out + (size_t)n * NCH * (POUT * POUT) + bin;

    #pragma unroll 4
    for (int cch = 0; cch < NCH; ++cch) {
        float v = w00 * base[o00] + w01 * base[o01]
                + w10 * base[o10] + w11 * base[o11];
        v += __shfl_xor(v, 1);
        v += __shfl_xor(v, 2);
        if (q == 0) op[cch * (POUT * POUT)] = v * 0.25f;
        o00 += HW; o01 += HW; o10 += HW; o11 += HW;
    }
}

extern "C" void kernel_launch(void* const* d_in, const int* in_sizes, int n_in,
                              void* d_out, int out_size, void* d_ws, size_t ws_size,
                              hipStream_t stream) {
    const float* f0 = (const float*)d_in[0];
    const float* f1 = (const float*)d_in[1];
    const float* f2 = (const float*)d_in[2];
    const float* f3 = (const float*)d_in[3];
    const float* props = (const float*)d_in[4];
    float* out = (float*)d_out;

    const int N = in_sizes[4] / 4;                 // 1024 boxes
    const int B = in_sizes[0] / (NCH * HW0);       // 2 images
    const int boxes_per_img = N / B;               // 512

    if (ws_size >= WS_NEED && B == 2 && N == 1024) {
        __half* wsh = (__half*)d_ws;
        transpose_fused_kernel<<<NBLK, 512, 0, stream>>>(f0, f1, f2, f3, wsh,
                                                         props, boxes_per_img, N);
        roi_gather_kernel<<<N, 256, 0, stream>>>(wsh, props, out, boxes_per_img);
    } else {
        roi_align_nchw_kernel<<<N, 256, 0, stream>>>(f0, f1, f2, f3, props, out, boxes_per_img);
    }
}